// Round 1
// baseline (186.174 us; speedup 1.0000x reference)
//
#include <hip/hip_runtime.h>
#include <math.h>

// Problem constants (from reference setup_inputs)
#define Bsz 16
#define Tsz 4
#define Nsz 1601
#define Dsz 1280
#define D4  (Dsz / 4)   // 320 float4 per row

// aspect_ratio is int64 in the reference; the harness doc says integers land
// as int32. Hedge: values are always in {1,2}, so in an int64 little-endian
// buffer every odd int32 word (the high half) is 0. Detect layout at runtime.
__device__ __forceinline__ void load_hw(const int* __restrict__ ar, int b, int& h, int& w) {
    int v0 = ar[2 * b];
    int v1 = ar[2 * b + 1];
    if (v1 != 0) {          // int32 layout: [h, w] directly
        h = v0; w = v1;
    } else {                // int64 layout: low words at 4b and 4b+2
        h = ar[4 * b];
        w = ar[4 * b + 2];
    }
}

// Kernel 1: materialize pe_scaled[bt][d] = valid ? emb[row,col,0,d]*tanh(gate) : 0
// grid = (B*T) blocks, D4 threads (one float4 each).
__global__ void build_pe_kernel(const float4* __restrict__ emb,
                                const int* __restrict__ ar,
                                const float* __restrict__ gate,
                                float4* __restrict__ pe) {
    int bt = blockIdx.x;            // 0..63
    int b = bt >> 2;
    int t = bt & 3;
    int h, w;
    load_hw(ar, b, h, w);
    float tg = tanhf(gate[0]);
    bool valid = t < h * w;
    int d4 = threadIdx.x;           // 0..319
    float4 v = make_float4(0.f, 0.f, 0.f, 0.f);
    if (valid) {
        int row = t / w;
        int col = t % w;
        float4 e = emb[(row * Tsz + col) * D4 + d4];
        v = make_float4(e.x * tg, e.y * tg, e.z * tg, e.w * tg);
    }
    pe[bt * D4 + d4] = v;
}

// Kernel 2: streaming add. grid = (N, B*T), block = D4 threads.
// Each lane: one float4 x-load (coalesced), one float4 pe-load (L1-hot), add, store.
__global__ void add_pe_kernel(const float4* __restrict__ x,
                              const float4* __restrict__ pe,
                              float4* __restrict__ out) {
    int bt = blockIdx.y;
    long idx = ((long)(bt * Nsz + blockIdx.x)) * D4 + threadIdx.x;
    float4 xv = x[idx];
    float4 pv = pe[bt * D4 + threadIdx.x];
    out[idx] = make_float4(xv.x + pv.x, xv.y + pv.y, xv.z + pv.z, xv.w + pv.w);
}

// Fallback (only if ws_size is unexpectedly tiny): everything inline.
__global__ void add_pe_inline_kernel(const float4* __restrict__ x,
                                     const float4* __restrict__ emb,
                                     const int* __restrict__ ar,
                                     const float* __restrict__ gate,
                                     float4* __restrict__ out) {
    int bt = blockIdx.y;
    int b = bt >> 2;
    int t = bt & 3;
    int h, w;
    load_hw(ar, b, h, w);
    float tg = tanhf(gate[0]);
    bool valid = t < h * w;
    float4 pv = make_float4(0.f, 0.f, 0.f, 0.f);
    if (valid) {
        int row = t / w;
        int col = t % w;
        float4 e = emb[(row * Tsz + col) * D4 + threadIdx.x];
        pv = make_float4(e.x * tg, e.y * tg, e.z * tg, e.w * tg);
    }
    long idx = ((long)(bt * Nsz + blockIdx.x)) * D4 + threadIdx.x;
    float4 xv = x[idx];
    out[idx] = make_float4(xv.x + pv.x, xv.y + pv.y, xv.z + pv.z, xv.w + pv.w);
}

extern "C" void kernel_launch(void* const* d_in, const int* in_sizes, int n_in,
                              void* d_out, int out_size, void* d_ws, size_t ws_size,
                              hipStream_t stream) {
    const float4* x    = (const float4*)d_in[0];   // (B,T,N,D) fp32
    const int*    ar   = (const int*)d_in[1];      // (B,2) int
    const float4* emb  = (const float4*)d_in[2];   // (T,T,1,D) fp32
    const float*  gate = (const float*)d_in[3];    // (1,) fp32
    float4* out = (float4*)d_out;

    const size_t pe_bytes = (size_t)Bsz * Tsz * Dsz * sizeof(float);  // 327,680 B
    if (ws_size >= pe_bytes) {
        float4* pe = (float4*)d_ws;
        build_pe_kernel<<<dim3(Bsz * Tsz), D4, 0, stream>>>(emb, ar, gate, pe);
        add_pe_kernel<<<dim3(Nsz, Bsz * Tsz), D4, 0, stream>>>(x, pe, out);
    } else {
        add_pe_inline_kernel<<<dim3(Nsz, Bsz * Tsz), D4, 0, stream>>>(x, emb, ar, gate, out);
    }
}